// Round 5
// baseline (299.896 us; speedup 1.0000x reference)
//
#include <hip/hip_runtime.h>

// softmax(relu(nv1 @ nv2), axis=1)
// nv1: [8192, 10] f32, nv2: [10, 8192] f32, out: [8192, 8192] f32
//
// Round 5 = round 3 with the nontemporal-store compile fix:
// __builtin_nontemporal_store requires a clang ext_vector pointer, not
// HIP's float4 class. Two-kernel split so the streaming kernel has ZERO
// barriers:
//   k1: rowinv[r] = 1 / sum_j exp(relu(nv1[r,:] . nv2[:,j]))   (32 KB to d_ws)
//   k2: out[r,j]  = exp(relu(nv1[r,:] . nv2[:,j])) * rowinv[r] (pure stream)
// Rationale: __syncthreads implies s_waitcnt vmcnt(0) -> every barrier in the
// round-2 kernel drained the output stores on the critical path (1 block/CU,
// nothing to overlap). k2 recomputes the cheap scores (80 FMA + 8 exp per
// thread-row, hidden under stores) and never synchronizes.

#define NODES 8192
#define RANK  10
#define TPB   1024
#define NWAVE (TPB / 64)            // 16
#define RPB   32                    // rows per block
#define NBLK  (NODES / RPB)         // 256
#define CHUNK 8                     // rows per reduction chunk in k1

typedef float f32x4 __attribute__((ext_vector_type(4)));

// ---------------------------------------------------------------- kernel 1
__global__ __launch_bounds__(TPB)
void rowsum_kernel(const float* __restrict__ nv1,
                   const float* __restrict__ nv2,
                   float* __restrict__ rowinv)
{
    const int t    = threadIdx.x;
    const int lane = t & 63;
    const int wave = t >> 6;
    const int row0 = blockIdx.x * RPB;

    // This thread's 8 nv2 columns, register-resident (80 VGPRs).
    float4 b[2][RANK];
#pragma unroll
    for (int g = 0; g < 2; ++g) {
        const int j = g * 4096 + t * 4;
#pragma unroll
        for (int k = 0; k < RANK; ++k)
            b[g][k] = *reinterpret_cast<const float4*>(nv2 + k * NODES + j);
    }

    __shared__ float red[NWAVE][RPB];

    for (int c = 0; c < RPB; c += CHUNK) {
        float psum[CHUNK];
#pragma unroll
        for (int r = 0; r < CHUNK; ++r) {
            const int row = row0 + c + r;            // uniform -> scalar loads
            float a[RANK];
#pragma unroll
            for (int k = 0; k < RANK; ++k) a[k] = nv1[row * RANK + k];

            float sum = 0.0f;
#pragma unroll
            for (int g = 0; g < 2; ++g) {
                float4 acc = make_float4(0.f, 0.f, 0.f, 0.f);
#pragma unroll
                for (int k = 0; k < RANK; ++k) {
                    acc.x = fmaf(a[k], b[g][k].x, acc.x);
                    acc.y = fmaf(a[k], b[g][k].y, acc.y);
                    acc.z = fmaf(a[k], b[g][k].z, acc.z);
                    acc.w = fmaf(a[k], b[g][k].w, acc.w);
                }
                sum += __expf(fmaxf(acc.x, 0.f)) + __expf(fmaxf(acc.y, 0.f))
                     + __expf(fmaxf(acc.z, 0.f)) + __expf(fmaxf(acc.w, 0.f));
            }
            psum[r] = sum;
        }
        // Wave-level butterfly; lane 0 parks the 8 row-partials in LDS.
        // Waves write disjoint LDS rows -> no barrier needed until the end.
#pragma unroll
        for (int r = 0; r < CHUNK; ++r) {
#pragma unroll
            for (int m = 32; m >= 1; m >>= 1)
                psum[r] += __shfl_xor(psum[r], m, 64);
        }
        if (lane == 0) {
#pragma unroll
            for (int r = 0; r < CHUNK; ++r) red[wave][c + r] = psum[r];
        }
    }

    __syncthreads();                 // the ONLY barrier in this kernel
    if (t < RPB) {
        float s = 0.0f;
#pragma unroll
        for (int w = 0; w < NWAVE; ++w) s += red[w][t];
        rowinv[row0 + t] = 1.0f / s;
    }
}

// ---------------------------------------------------------------- kernel 2
__global__ __launch_bounds__(TPB)
void stream_kernel(const float* __restrict__ nv1,
                   const float* __restrict__ nv2,
                   const float* __restrict__ rowinv,
                   float* __restrict__ out)
{
    const int t    = threadIdx.x;
    const int row0 = blockIdx.x * RPB;

    float4 b[2][RANK];
#pragma unroll
    for (int g = 0; g < 2; ++g) {
        const int j = g * 4096 + t * 4;
#pragma unroll
        for (int k = 0; k < RANK; ++k)
            b[g][k] = *reinterpret_cast<const float4*>(nv2 + k * NODES + j);
    }

#pragma unroll 2
    for (int r = 0; r < RPB; ++r) {
        const int row = row0 + r;                    // uniform
        const float inv = rowinv[row];               // uniform scalar load
        float a[RANK];
#pragma unroll
        for (int k = 0; k < RANK; ++k) a[k] = nv1[row * RANK + k];

        float* __restrict__ orow = out + (size_t)row * NODES;
#pragma unroll
        for (int g = 0; g < 2; ++g) {
            const int j = g * 4096 + t * 4;
            float4 acc = make_float4(0.f, 0.f, 0.f, 0.f);
#pragma unroll
            for (int k = 0; k < RANK; ++k) {
                acc.x = fmaf(a[k], b[g][k].x, acc.x);
                acc.y = fmaf(a[k], b[g][k].y, acc.y);
                acc.z = fmaf(a[k], b[g][k].z, acc.z);
                acc.w = fmaf(a[k], b[g][k].w, acc.w);
            }
            f32x4 o;
            o.x = __expf(fmaxf(acc.x, 0.f)) * inv;
            o.y = __expf(fmaxf(acc.y, 0.f)) * inv;
            o.z = __expf(fmaxf(acc.z, 0.f)) * inv;
            o.w = __expf(fmaxf(acc.w, 0.f)) * inv;
            __builtin_nontemporal_store(o, reinterpret_cast<f32x4*>(orow + j));
        }
    }
}

extern "C" void kernel_launch(void* const* d_in, const int* in_sizes, int n_in,
                              void* d_out, int out_size, void* d_ws, size_t ws_size,
                              hipStream_t stream)
{
    const float* nv1 = (const float*)d_in[0];   // [8192, 10]
    const float* nv2 = (const float*)d_in[1];   // [10, 8192]
    float* out    = (float*)d_out;              // [8192, 8192]
    float* rowinv = (float*)d_ws;               // 8192 floats of scratch

    rowsum_kernel<<<NBLK, TPB, 0, stream>>>(nv1, nv2, rowinv);
    stream_kernel<<<NBLK, TPB, 0, stream>>>(nv1, nv2, rowinv, out);
}

// Round 6
// 288.115 us; speedup vs baseline: 1.0409x; 1.0409x over previous
//
#include <hip/hip_runtime.h>

// softmax(relu(nv1 @ nv2), axis=1)
// nv1: [8192, 10] f32, nv2: [10, 8192] f32, out: [8192, 8192] f32
//
// Round 6: k2 reshaped to match the harness fill kernel's occupancy profile.
// r2 (barriers, plain stores) == r5 (no barriers, NT stores) == ~300 us proved
// the bottleneck is neither barriers nor store type. Common factor was
// TPB=1024 + 80-VGPR b-slice -> 1 block/CU, 4 waves/SIMD. New k2: TPB=256,
// 4 cols/thread (40 VGPR b-slice, ~56 total), 8 rows/block -> 8 blocks/CU,
// 32 waves/CU, plain float4 stores. nv2 L2 traffic = 10/8 x output = 335 MB.
//   k1: rowinv[r] = 1/sum_j exp(relu(nv1[r,:] . nv2[:,j]))  (unchanged)
//   k2: out[r,j]  = exp(relu(nv1[r,:] . nv2[:,j])) * rowinv[r]

#define NODES 8192
#define RANK  10

// ---------------- kernel 1: row sums (TPB=1024, full row per block) --------
#define K1_TPB   1024
#define K1_NWAVE (K1_TPB / 64)        // 16
#define K1_RPB   32                   // rows per block
#define K1_NBLK  (NODES / K1_RPB)     // 256
#define K1_CHUNK 8

__global__ __launch_bounds__(K1_TPB)
void rowsum_kernel(const float* __restrict__ nv1,
                   const float* __restrict__ nv2,
                   float* __restrict__ rowinv)
{
    const int t    = threadIdx.x;
    const int lane = t & 63;
    const int wave = t >> 6;
    const int row0 = blockIdx.x * K1_RPB;

    // This thread's 8 nv2 columns, register-resident (80 VGPRs).
    float4 b[2][RANK];
#pragma unroll
    for (int g = 0; g < 2; ++g) {
        const int j = g * 4096 + t * 4;
#pragma unroll
        for (int k = 0; k < RANK; ++k)
            b[g][k] = *reinterpret_cast<const float4*>(nv2 + k * NODES + j);
    }

    __shared__ float red[K1_NWAVE][K1_RPB];

    for (int c = 0; c < K1_RPB; c += K1_CHUNK) {
        float psum[K1_CHUNK];
#pragma unroll
        for (int r = 0; r < K1_CHUNK; ++r) {
            const int row = row0 + c + r;            // uniform -> scalar loads
            float a[RANK];
#pragma unroll
            for (int k = 0; k < RANK; ++k) a[k] = nv1[row * RANK + k];

            float sum = 0.0f;
#pragma unroll
            for (int g = 0; g < 2; ++g) {
                float4 acc = make_float4(0.f, 0.f, 0.f, 0.f);
#pragma unroll
                for (int k = 0; k < RANK; ++k) {
                    acc.x = fmaf(a[k], b[g][k].x, acc.x);
                    acc.y = fmaf(a[k], b[g][k].y, acc.y);
                    acc.z = fmaf(a[k], b[g][k].z, acc.z);
                    acc.w = fmaf(a[k], b[g][k].w, acc.w);
                }
                sum += __expf(fmaxf(acc.x, 0.f)) + __expf(fmaxf(acc.y, 0.f))
                     + __expf(fmaxf(acc.z, 0.f)) + __expf(fmaxf(acc.w, 0.f));
            }
            psum[r] = sum;
        }
#pragma unroll
        for (int r = 0; r < K1_CHUNK; ++r) {
#pragma unroll
            for (int m = 32; m >= 1; m >>= 1)
                psum[r] += __shfl_xor(psum[r], m, 64);
        }
        if (lane == 0) {
#pragma unroll
            for (int r = 0; r < K1_CHUNK; ++r) red[wave][c + r] = psum[r];
        }
    }

    __syncthreads();                 // the ONLY barrier
    if (t < K1_RPB) {
        float s = 0.0f;
#pragma unroll
        for (int w = 0; w < K1_NWAVE; ++w) s += red[w][t];
        rowinv[row0 + t] = 1.0f / s;
    }
}

// ---------------- kernel 2: fill-shaped streamer ---------------------------
// TPB=256, 4 cols/thread, 8 rows/block. Grid = (8192/8 rowblks) x 8 col-segs.
#define K2_TPB  256
#define K2_RPB  8                     // rows per block
#define K2_SEGS (NODES / (K2_TPB * 4))          // 8 column segments
#define K2_NBLK ((NODES / K2_RPB) * K2_SEGS)    // 8192 blocks

__global__ __launch_bounds__(K2_TPB, 8)
void stream_kernel(const float* __restrict__ nv1,
                   const float* __restrict__ nv2,
                   const float* __restrict__ rowinv,
                   float* __restrict__ out)
{
    const int t      = threadIdx.x;
    const int seg    = blockIdx.x & (K2_SEGS - 1);
    const int rowblk = blockIdx.x >> 3;           // log2(K2_SEGS)
    const int row0   = rowblk * K2_RPB;
    const int j      = seg * (K2_TPB * 4) + t * 4;

    // 4-column nv2 slice: 10 x float4 = 40 VGPRs, loaded once, L2-hot.
    float4 b[RANK];
#pragma unroll
    for (int k = 0; k < RANK; ++k)
        b[k] = *reinterpret_cast<const float4*>(nv2 + k * NODES + j);

#pragma unroll 2
    for (int r = 0; r < K2_RPB; ++r) {
        const int row = row0 + r;                 // uniform
        const float inv = rowinv[row];            // uniform -> s_load
        float a[RANK];
#pragma unroll
        for (int k = 0; k < RANK; ++k) a[k] = nv1[row * RANK + k];  // s_loads

        float4 acc = make_float4(0.f, 0.f, 0.f, 0.f);
#pragma unroll
        for (int k = 0; k < RANK; ++k) {
            acc.x = fmaf(a[k], b[k].x, acc.x);
            acc.y = fmaf(a[k], b[k].y, acc.y);
            acc.z = fmaf(a[k], b[k].z, acc.z);
            acc.w = fmaf(a[k], b[k].w, acc.w);
        }
        float4 o;
        o.x = __expf(fmaxf(acc.x, 0.f)) * inv;
        o.y = __expf(fmaxf(acc.y, 0.f)) * inv;
        o.z = __expf(fmaxf(acc.z, 0.f)) * inv;
        o.w = __expf(fmaxf(acc.w, 0.f)) * inv;
        *reinterpret_cast<float4*>(out + (size_t)row * NODES + j) = o;
    }
}

extern "C" void kernel_launch(void* const* d_in, const int* in_sizes, int n_in,
                              void* d_out, int out_size, void* d_ws, size_t ws_size,
                              hipStream_t stream)
{
    const float* nv1 = (const float*)d_in[0];   // [8192, 10]
    const float* nv2 = (const float*)d_in[1];   // [10, 8192]
    float* out    = (float*)d_out;              // [8192, 8192]
    float* rowinv = (float*)d_ws;               // 8192 floats of scratch

    rowsum_kernel<<<K1_NBLK, K1_TPB, 0, stream>>>(nv1, nv2, rowinv);
    stream_kernel<<<K2_NBLK, K2_TPB, 0, stream>>>(nv1, nv2, rowinv, out);
}